// Round 2
// baseline (71.646 us; speedup 1.0000x reference)
//
#include <hip/hip_runtime.h>

#define IMG 128
#define NBALL 21

// RNE round-to-bf16 grid, value returned in fp32.
__device__ __forceinline__ float bf16_snap(float f) {
    union { float f; unsigned int u; } v; v.f = f;
    unsigned int u = v.u;
    u += 0x7fffu + ((u >> 16) & 1u);   // round to nearest even
    v.u = u & 0xFFFF0000u;
    return v.f;
}

// Phase 1: per image (128 blocks) — project balls, emit proj output, and
// stash per-row compacted candidate lists {x, z, dy2, r2} + count INSIDE the
// row's own depth-pixel area (floats [0,84) = slots, [84] = count). That
// region is read and then fully overwritten by the one raster block owning
// the row, so no workspace buffer is needed (round-1 crash suspect).
__global__ __launch_bounds__(128) void prep_kernel(
    const float* __restrict__ cam,    // [B,V,4,4]
    const float* __restrict__ inv,    // [B,V,4,4]
    const float* __restrict__ joints, // [B,V,J,3]
    const float* __restrict__ rads,   // [J]
    float* __restrict__ out)          // depth [128][128][128] ++ proj [128][J][3]
{
#pragma clang fp contract(off)
    constexpr int V = 4;
    const int img = blockIdx.x;       // ((b*V)+i)*V + j
    const int b = img >> 4;
    const int i = (img >> 2) & 3;
    const int j = img & 3;
    const int t = threadIdx.x;

    __shared__ float4 sball[NBALL];   // {x, y, z, r2}

    if (t < NBALL) {
        const float4* invp4 = (const float4*)(inv + ((b * V + j) << 4));
        const float4* camp4 = (const float4*)(cam + ((b * V + i) << 4));
        float M[4][4], C[4][4];
        #pragma unroll
        for (int a = 0; a < 4; ++a) {
            const float4 mr = invp4[a], cr = camp4[a];
            M[a][0] = mr.x; M[a][1] = mr.y; M[a][2] = mr.z; M[a][3] = mr.w;
            C[a][0] = cr.x; C[a][1] = cr.y; C[a][2] = cr.z; C[a][3] = cr.w;
        }

        // mutual[b,i,j,x,z] = sum_y inv[b,j,x,y]*cam[b,i,y,z]
        // mul, then ascending FMA chain over y (verified numeric model).
        float R[3][4];
        #pragma unroll
        for (int x = 0; x < 3; ++x) {
            #pragma unroll
            for (int zc = 0; zc < 4; ++zc) {
                float s = __fmul_rn(M[x][0], C[0][zc]);
                s = __fmaf_rn(M[x][1], C[1][zc], s);
                s = __fmaf_rn(M[x][2], C[2][zc], s);
                s = __fmaf_rn(M[x][3], C[3][zc], s);
                R[x][zc] = s;
            }
        }

        const float* jp = joints + (((b * V + i) * NBALL + t) * 3);
        const float jx = jp[0], jy = jp[1], jz = jp[2];

        float p[3];
        #pragma unroll
        for (int x = 0; x < 3; ++x) {
            float s = __fmul_rn(R[x][0], jx);   // K=3 FMA chain
            s = __fmaf_rn(R[x][1], jy, s);
            s = __fadd_rn(__fmaf_rn(R[x][2], jz, s), R[x][3]); // +t[x] separate
            p[x] = s;
        }
        const float r = rads[t];
        sball[t] = make_float4(p[0], p[1], p[2], __fmul_rn(r, r));

        float* po = out + (128 * IMG * IMG) + (img * NBALL + t) * 3;
        po[0] = bf16_snap(p[0]);
        po[1] = bf16_snap(p[1]);
        po[2] = bf16_snap(p[2]);
    }
    __syncthreads();

    // One thread per row: compact candidates (ascending k preserves min order).
    // Skip is exact: dy2 >= r2 => RN(dx2+dy2) >= dy2 >= r2 (RN monotone).
    const float v = (float)t;
    float* rowbase = out + img * (IMG * IMG) + (t << 7);
    float4* rp4 = (float4*)rowbase;
    int cnt = 0;
    #pragma unroll
    for (int k = 0; k < NBALL; ++k) {
        const float4 bl = sball[k];            // broadcast ds_read
        const float dy  = __fsub_rn(v, bl.y);
        const float dy2 = __fmul_rn(dy, dy);
        if (dy2 < bl.w) {
            rp4[cnt] = make_float4(bl.x, bl.z, dy2, bl.w);  // {x, z, dy2, r2}
            ++cnt;
        }
    }
    for (int s = cnt; s < 8; ++s)
        rp4[s] = make_float4(0.f, 0.f, 0.f, 0.f);  // r2=0 pad => no-op slot
    rowbase[84] = __int_as_float(cnt);             // count after slot 20
}

// Phase 2: raster. 2048 blocks x 256 threads, one row per 32-lane group,
// 4 px/thread. No LDS tile, no data-dependent inner flow for cnt<=8: load
// 8 slots + tail float4 + cnt, drain loads, barrier, then compute + store
// (overwriting the stash). Tail slots (rare) broadcast via shfl width 32.
__global__ __launch_bounds__(256) void raster_kernel(float* __restrict__ out)
{
#pragma clang fp contract(off)
    const int bid  = blockIdx.x;
    const int img  = bid >> 4;         // 0..127
    const int slab = bid & 15;         // 8-row slab
    const int t    = threadIdx.x;
    const int lane = t & 31;
    const int row  = slab * 8 + (t >> 5);
    const int col  = lane << 2;        // 4 consecutive px

    float* rowbase = out + img * (IMG * IMG) + (row << 7);
    const float4* rp4 = (const float4*)rowbase;

    // Issue all reads of the stash up front (independent, L1/L2 broadcast).
    float4 cd[8];
    #pragma unroll
    for (int s = 0; s < 8; ++s) cd[s] = rp4[s];
    const int cnt = __float_as_int(rowbase[84]);
    float4 ts = rp4[8 + (lane < 13 ? lane : 12)];   // lane l holds slot 8+l

    // All stash reads must retire to registers before ANY lane of this
    // block stores pixels over the stash region.
    asm volatile("s_waitcnt vmcnt(0)" ::: "memory");
    __syncthreads();

    const float u0 = (float)col;
    float best0 = 1000000.0f, best1 = 1000000.0f;
    float best2 = 1000000.0f, best3 = 1000000.0f;

    // bl = {x, z, dy2, r2}
    auto doball = [&](const float4 bl) {
        #pragma unroll
        for (int c = 0; c < 4; ++c) {
            const float u  = __fadd_rn(u0, (float)c);     // exact ints
            const float dx = __fsub_rn(u, bl.x);
            const float d2 = __fadd_rn(__fmul_rn(dx, dx), bl.z);
            if (d2 < bl.w) {
                const float dep =
                    __fsub_rn(bl.y, __fsqrt_rn(__fsub_rn(bl.w, d2)));
                if (c == 0) best0 = fminf(best0, dep);
                if (c == 1) best1 = fminf(best1, dep);
                if (c == 2) best2 = fminf(best2, dep);
                if (c == 3) best3 = fminf(best3, dep);
            }
        }
    };

    #pragma unroll
    for (int s = 0; s < 8; ++s) doball(cd[s]);

    if (cnt > 8) {                      // rare (~0.2% of rows), <= 21 total
        for (int s = 8; s < cnt; ++s) {
            float4 bl;
            bl.x = __shfl(ts.x, s - 8, 32);
            bl.y = __shfl(ts.y, s - 8, 32);
            bl.z = __shfl(ts.z, s - 8, 32);
            bl.w = __shfl(ts.w, s - 8, 32);
            doball(bl);
        }
    }

    float4 o;
    o.x = bf16_snap(best0); o.y = bf16_snap(best1);
    o.z = bf16_snap(best2); o.w = bf16_snap(best3);
    *(float4*)(rowbase + col) = o;      // 16 B coalesced store
}

extern "C" void kernel_launch(void* const* d_in, const int* in_sizes, int n_in,
                              void* d_out, int out_size, void* d_ws, size_t ws_size,
                              hipStream_t stream) {
    const float* cam    = (const float*)d_in[0]; // camera_poses
    const float* inv    = (const float*)d_in[1]; // inv_camera_poses
    const float* joints = (const float*)d_in[2];
    const float* rads   = (const float*)d_in[3];
    float* out = (float*)d_out;

    hipLaunchKernelGGL(prep_kernel, dim3(128), dim3(128), 0, stream,
                       cam, inv, joints, rads, out);
    hipLaunchKernelGGL(raster_kernel, dim3(2048), dim3(256), 0, stream, out);
}

// Round 3
// 68.976 us; speedup vs baseline: 1.0387x; 1.0387x over previous
//
#include <hip/hip_runtime.h>

#define IMG 128
#define NBALL 21

// RNE round-to-bf16 grid, value returned in fp32.
__device__ __forceinline__ float bf16_snap(float f) {
    union { float f; unsigned int u; } v; v.f = f;
    unsigned int u = v.u;
    u += 0x7fffu + ((u >> 16) & 1u);   // round to nearest even
    v.u = u & 0xFFFF0000u;
    return v.f;
}

// Single kernel (one dispatch — round 2 showed a second launch costs ~5us).
// Per block: 16-row slab of one image.
//   Phase A: lanes 0..20 project balls (verified numeric model), proj out.
//   Phase B: lanes 0..15 compact per-row candidate lists into LDS
//            slots[row][s] = {x, z, dy2, r2}, zero-padded to 8 (r2=0 no-op).
//   Phase C: branchless raster — 8 statically-addressed LDS broadcast reads
//            (pipelined, single wait), unconditional predicated math, rare
//            in-LDS tail for cnt>8. No per-candidate dependent chain, no
//            ctz divergence (the round-0 kernel's serialization).
__global__ __launch_bounds__(256) void mutual_proj_kernel(
    const float* __restrict__ cam,    // camera_poses    [B,V,4,4] fp32
    const float* __restrict__ inv,    // inv_camera_poses[B,V,4,4] fp32
    const float* __restrict__ joints, // [B,V,J,3] fp32
    const float* __restrict__ rads,   // [J] fp32
    float* __restrict__ out)          // fp32: depth [128,128,128] ++ proj [128,J,3]
{
#pragma clang fp contract(off)
    constexpr int V = 4, J = NBALL;
    const int bid  = blockIdx.x;
    const int img  = bid >> 3;      // 0..127  == ((b*V)+i)*V + j
    const int slab = bid & 7;       // 16-row slab within the image
    const int b = img >> 4;
    const int i = (img >> 2) & 3;
    const int j = img & 3;
    const int t = threadIdx.x;

    __shared__ float4 sball[J];        // {x, y, z, r2} per ball
    __shared__ float4 slots[16][J];    // per-row compacted {x, z, dy2, r2}
    __shared__ int    scnt[16];

    if (t < J) {
        const float4* invp4 = (const float4*)(inv + ((b * V + j) << 4));
        const float4* camp4 = (const float4*)(cam + ((b * V + i) << 4));
        float M[4][4], C[4][4];
        #pragma unroll
        for (int a = 0; a < 4; ++a) {
            const float4 mr = invp4[a], cr = camp4[a];
            M[a][0] = mr.x; M[a][1] = mr.y; M[a][2] = mr.z; M[a][3] = mr.w;
            C[a][0] = cr.x; C[a][1] = cr.y; C[a][2] = cr.z; C[a][3] = cr.w;
        }

        // mutual[b,i,j,x,z] = sum_y inv[b,j,x,y]*cam[b,i,y,z]
        // mul, then ascending FMA chain over y (verified numeric model).
        float R[3][4];
        #pragma unroll
        for (int x = 0; x < 3; ++x) {
            #pragma unroll
            for (int zc = 0; zc < 4; ++zc) {
                float s = __fmul_rn(M[x][0], C[0][zc]);
                s = __fmaf_rn(M[x][1], C[1][zc], s);
                s = __fmaf_rn(M[x][2], C[2][zc], s);
                s = __fmaf_rn(M[x][3], C[3][zc], s);
                R[x][zc] = s;
            }
        }

        const float* jp = joints + (((b * V + i) * J + t) * 3);
        const float jx = jp[0], jy = jp[1], jz = jp[2];

        float p[3];
        #pragma unroll
        for (int x = 0; x < 3; ++x) {
            float s = __fmul_rn(R[x][0], jx);   // K=3 FMA chain
            s = __fmaf_rn(R[x][1], jy, s);
            s = __fmaf_rn(R[x][2], jz, s);
            s = __fadd_rn(s, R[x][3]);          // + t[x], separate add
            p[x] = s;
        }
        const float r = rads[t];
        sball[t] = make_float4(p[0], p[1], p[2], __fmul_rn(r, r));

        if (slab == 0) {
            float* po = out + (128 * IMG * IMG) + (img * J + t) * 3;
            po[0] = bf16_snap(p[0]);
            po[1] = bf16_snap(p[1]);
            po[2] = bf16_snap(p[2]);
        }
    }
    __syncthreads();

    // Phase B: one thread per row of this slab compacts candidates
    // (ascending k preserves the verified fmin order).
    // Skip is exact: dy2 >= r2  =>  RN(dx2+dy2) >= dy2 >= r2 (RN monotone).
    if (t < 16) {
        const int   row = slab * 16 + t;
        const float v   = (float)row;
        int cnt = 0;
        #pragma unroll
        for (int k = 0; k < J; ++k) {
            const float4 bl = sball[k];          // broadcast ds_read
            const float dy  = __fsub_rn(v, bl.y);
            const float dy2 = __fmul_rn(dy, dy);
            if (dy2 < bl.w) {
                slots[t][cnt] = make_float4(bl.x, bl.z, dy2, bl.w);
                ++cnt;
            }
        }
        for (int s = cnt; s < 8; ++s)
            slots[t][s] = make_float4(0.f, 0.f, 0.f, 0.f);  // r2=0 => no-op
        scnt[t] = cnt;
    }
    __syncthreads();

    float* dout = out + img * (IMG * IMG);
    const int pbase = slab * 2048;            // 16 rows * 128 cols
    #pragma unroll
    for (int it = 0; it < 2; ++it) {
        const int base = pbase + it * 1024 + t * 4;  // 4 consecutive px
        const int r16  = ((it * 1024 + t * 4) >> 7) & 15;
        const float u0 = (float)(base & 127);

        float best0 = 1000000.0f, best1 = 1000000.0f;
        float best2 = 1000000.0f, best3 = 1000000.0f;

        // bl = {x, z, dy2, r2}
        auto doball = [&](const float4 bl) {
            #pragma unroll
            for (int c = 0; c < 4; ++c) {
                const float u  = __fadd_rn(u0, (float)c);  // exact ints
                const float dx = __fsub_rn(u, bl.x);
                const float d2 = __fadd_rn(__fmul_rn(dx, dx), bl.z);
                if (d2 < bl.w) {
                    const float dep =
                        __fsub_rn(bl.y, __fsqrt_rn(__fsub_rn(bl.w, d2)));
                    if (c == 0) best0 = fminf(best0, dep);
                    if (c == 1) best1 = fminf(best1, dep);
                    if (c == 2) best2 = fminf(best2, dep);
                    if (c == 3) best3 = fminf(best3, dep);
                }
            }
        };

        const int cnt = scnt[r16];
        // 8 broadcast LDS reads at static offsets — pipelined, single wait.
        float4 cd[8];
        #pragma unroll
        for (int s = 0; s < 8; ++s) cd[s] = slots[r16][s];
        #pragma unroll
        for (int s = 0; s < 8; ++s) doball(cd[s]);

        if (cnt > 8) {                      // rare (~0.2% of rows)
            for (int s = 8; s < cnt; ++s) doball(slots[r16][s]);
        }

        float4 o;
        o.x = bf16_snap(best0); o.y = bf16_snap(best1);
        o.z = bf16_snap(best2); o.w = bf16_snap(best3);
        *(float4*)(dout + base) = o;           // 16 B coalesced store
    }
}

extern "C" void kernel_launch(void* const* d_in, const int* in_sizes, int n_in,
                              void* d_out, int out_size, void* d_ws, size_t ws_size,
                              hipStream_t stream) {
    const float* cam    = (const float*)d_in[0]; // camera_poses
    const float* inv    = (const float*)d_in[1]; // inv_camera_poses
    const float* joints = (const float*)d_in[2];
    const float* rads   = (const float*)d_in[3];
    float* out = (float*)d_out;

    dim3 grid(128 * 8);   // 128 images * 8 slabs
    dim3 block(256);
    hipLaunchKernelGGL(mutual_proj_kernel, grid, block, 0, stream,
                       cam, inv, joints, rads, out);
}

// Round 4
// 66.869 us; speedup vs baseline: 1.0714x; 1.0315x over previous
//
#include <hip/hip_runtime.h>

#define IMG 128
#define NBALL 21

// RNE round-to-bf16 grid, value returned in fp32.
__device__ __forceinline__ float bf16_snap(float f) {
    union { float f; unsigned int u; } v; v.f = f;
    unsigned int u = v.u;
    u += 0x7fffu + ((u >> 16) & 1u);   // round to nearest even
    v.u = u & 0xFFFF0000u;
    return v.f;
}

// Round-0 structure (best measured) + micro-opts:
//  - 8 px/thread, ONE row per thread -> single mask walk (was 2 serial walks)
//  - per-slab mask (16 rows) instead of whole-image (128 rows)
//  - first-4 candidate indices extracted branchlessly, 4 independent LDS
//    reads issued together (one wait, not a serial ctz->read->wait chain);
//    predicated processing; rare serial tail for cnt>4 (~5% of rows).
// Numeric model unchanged (verified, absmax 0.0625): fp32 mul + ascending
// FMA chains for einsums; raster = fp32 RN ops; outputs bf16-snapped.
__global__ __launch_bounds__(256) void mutual_proj_kernel(
    const float* __restrict__ cam,    // camera_poses    [B,V,4,4] fp32
    const float* __restrict__ inv,    // inv_camera_poses[B,V,4,4] fp32
    const float* __restrict__ joints, // [B,V,J,3] fp32
    const float* __restrict__ rads,   // [J] fp32
    float* __restrict__ out)          // fp32: depth [128,128,128] ++ proj [128,J,3]
{
#pragma clang fp contract(off)
    constexpr int V = 4, J = NBALL;
    const int bid  = blockIdx.x;
    const int img  = bid >> 3;      // 0..127  == ((b*V)+i)*V + j
    const int slab = bid & 7;       // 16-row slab within the image
    const int b = img >> 4;
    const int i = (img >> 2) & 3;
    const int j = img & 3;
    const int t = threadIdx.x;

    __shared__ float4   sball[J];    // {x, y, z, r2} per ball
    __shared__ unsigned smask[16];   // per-row active-ball bitmask (this slab)

    if (t < J) {
        const float4* invp4 = (const float4*)(inv + ((b * V + j) << 4));
        const float4* camp4 = (const float4*)(cam + ((b * V + i) << 4));
        float M[4][4], C[4][4];
        #pragma unroll
        for (int a = 0; a < 4; ++a) {
            const float4 mr = invp4[a], cr = camp4[a];
            M[a][0] = mr.x; M[a][1] = mr.y; M[a][2] = mr.z; M[a][3] = mr.w;
            C[a][0] = cr.x; C[a][1] = cr.y; C[a][2] = cr.z; C[a][3] = cr.w;
        }

        // mutual[b,i,j,x,z] = sum_y inv[b,j,x,y]*cam[b,i,y,z]
        // mul, then ascending FMA chain over y (verified vs ref).
        float R[3][4];
        #pragma unroll
        for (int x = 0; x < 3; ++x) {
            #pragma unroll
            for (int zc = 0; zc < 4; ++zc) {
                float s = __fmul_rn(M[x][0], C[0][zc]);
                s = __fmaf_rn(M[x][1], C[1][zc], s);
                s = __fmaf_rn(M[x][2], C[2][zc], s);
                s = __fmaf_rn(M[x][3], C[3][zc], s);
                R[x][zc] = s;
            }
        }

        const float* jp = joints + (((b * V + i) * J + t) * 3);
        const float jx = jp[0], jy = jp[1], jz = jp[2];

        float p[3];
        #pragma unroll
        for (int x = 0; x < 3; ++x) {
            float s = __fmul_rn(R[x][0], jx);   // K=3 FMA chain
            s = __fmaf_rn(R[x][1], jy, s);
            s = __fmaf_rn(R[x][2], jz, s);
            s = __fadd_rn(s, R[x][3]);          // + t[x], separate add
            p[x] = s;
        }
        const float r = rads[t];
        sball[t] = make_float4(p[0], p[1], p[2], __fmul_rn(r, r));

        if (slab == 0) {
            float* po = out + (128 * IMG * IMG) + (img * J + t) * 3;
            po[0] = bf16_snap(p[0]);
            po[1] = bf16_snap(p[1]);
            po[2] = bf16_snap(p[2]);
        }
    }
    __syncthreads();

    // Per-row candidate bitmask, only this slab's 16 rows.
    // Skip is exact: dy2 >= r2  =>  RN(dx2+dy2) >= dy2 >= r2 (RN monotone).
    if (t < 16) {
        const float v = (float)(slab * 16 + t);
        unsigned m = 0;
        #pragma unroll
        for (int k = 0; k < J; ++k) {
            const float dy  = __fsub_rn(v, sball[k].y);
            const float dy2 = __fmul_rn(dy, dy);
            if (dy2 < sball[k].w) m |= (1u << k);
        }
        smask[t] = m;
    }
    __syncthreads();

    // Raster: thread t owns row slab*16 + (t>>4), cols (t&15)*8 .. +7.
    const int r16 = t >> 4;
    const int row = slab * 16 + r16;
    const int col = (t & 15) << 3;
    const float v = (float)row;

    float u[8];
    #pragma unroll
    for (int c = 0; c < 8; ++c) u[c] = __fadd_rn((float)col, (float)c); // exact

    float best[8];
    #pragma unroll
    for (int c = 0; c < 8; ++c) best[c] = 1000000.0f;

    // bl = {x, y, z, r2}
    auto doball = [&](const float4 bl) {
        const float dy  = __fsub_rn(v, bl.y);
        const float dy2 = __fmul_rn(dy, dy);       // shared by the 8 px
        #pragma unroll
        for (int c = 0; c < 8; ++c) {
            const float dx = __fsub_rn(u[c], bl.x);
            const float d2 = __fadd_rn(__fmul_rn(dx, dx), dy2);
            if (d2 < bl.w) {
                const float dep =
                    __fsub_rn(bl.z, __fsqrt_rn(__fsub_rn(bl.w, d2)));
                best[c] = fminf(best[c], dep);
            }
        }
    };

    const unsigned m = smask[r16];
    const int cnt = __popc(m);

    // Extract first 4 candidate indices branchlessly (ascending k), issue
    // the 4 LDS reads together (independent -> pipelined, single wait).
    unsigned mm = m;
    int i0 = (int)__builtin_ctz(mm | 0x80000000u); i0 = i0 > 20 ? 20 : i0; mm &= mm - 1u;
    int i1 = (int)__builtin_ctz(mm | 0x80000000u); i1 = i1 > 20 ? 20 : i1; mm &= mm - 1u;
    int i2 = (int)__builtin_ctz(mm | 0x80000000u); i2 = i2 > 20 ? 20 : i2; mm &= mm - 1u;
    int i3 = (int)__builtin_ctz(mm | 0x80000000u); i3 = i3 > 20 ? 20 : i3; mm &= mm - 1u;
    const float4 b0 = sball[i0];
    const float4 b1 = sball[i1];
    const float4 b2 = sball[i2];
    const float4 b3 = sball[i3];

    if (cnt > 0) doball(b0);
    if (cnt > 1) doball(b1);
    if (cnt > 2) doball(b2);
    if (cnt > 3) doball(b3);
    if (cnt > 4) {                      // rare (~5% of rows)
        while (mm) {
            const int k = __builtin_ctz(mm);
            mm &= mm - 1u;
            doball(sball[k]);
        }
    }

    float* dout = out + img * (IMG * IMG) + (row << 7) + col;
    float4 oA, oB;
    oA.x = bf16_snap(best[0]); oA.y = bf16_snap(best[1]);
    oA.z = bf16_snap(best[2]); oA.w = bf16_snap(best[3]);
    oB.x = bf16_snap(best[4]); oB.y = bf16_snap(best[5]);
    oB.z = bf16_snap(best[6]); oB.w = bf16_snap(best[7]);
    *(float4*)dout       = oA;          // 2 x 16 B stores, row-contiguous
    *(float4*)(dout + 4) = oB;
}

extern "C" void kernel_launch(void* const* d_in, const int* in_sizes, int n_in,
                              void* d_out, int out_size, void* d_ws, size_t ws_size,
                              hipStream_t stream) {
    const float* cam    = (const float*)d_in[0]; // camera_poses
    const float* inv    = (const float*)d_in[1]; // inv_camera_poses
    const float* joints = (const float*)d_in[2];
    const float* rads   = (const float*)d_in[3];
    float* out = (float*)d_out;

    dim3 grid(128 * 8);   // 128 images * 8 slabs
    dim3 block(256);
    hipLaunchKernelGGL(mutual_proj_kernel, grid, block, 0, stream,
                       cam, inv, joints, rads, out);
}